// Round 1
// baseline (352.739 us; speedup 1.0000x reference)
//
#include <hip/hip_runtime.h>
#include <cstdint>
#include <cstddef>

typedef __attribute__((ext_vector_type(4))) float f32x4;
typedef __attribute__((ext_vector_type(8))) short s16x8;
typedef __attribute__((ext_vector_type(4))) short s16x4;

#define DEV __device__ __forceinline__

DEV short f2bf(float f) {
    unsigned u = __builtin_bit_cast(unsigned, f);
    unsigned r = (u + 0x7FFFu + ((u >> 16) & 1u)) >> 16;
    return (short)r;
}

DEV void gload_lds16(const void* g, void* l) {
    __builtin_amdgcn_global_load_lds(
        (const __attribute__((address_space(1))) unsigned int*)g,
        (__attribute__((address_space(3))) unsigned int*)l, 16, 0, 0);
}

// ---------------- conversion / packing kernels ----------------

__global__ void k_cvt_x(const float* __restrict__ X, short* __restrict__ Xb, int n4) {
    int stride = gridDim.x * blockDim.x;
    for (int i = blockIdx.x * blockDim.x + threadIdx.x; i < n4; i += stride) {
        f32x4 v = *(const f32x4*)&X[i * 4];
        s16x4 s;
#pragma unroll
        for (int j = 0; j < 4; ++j) s[j] = f2bf(v[j]);
        *(s16x4*)&Xb[i * 4] = s;
    }
}

// Wbt[c][d] = W_t[h, d, k]  with c = t*1024 + h*64 + k,  t selects Wq/Wk/Wv
__global__ void k_pack_wqkv(const float* __restrict__ Wq, const float* __restrict__ Wk,
                            const float* __restrict__ Wv, short* __restrict__ Wbt, int n) {
    int stride = gridDim.x * blockDim.x;
    for (int o = blockIdx.x * blockDim.x + threadIdx.x; o < n; o += stride) {
        int c = o >> 10, d = o & 1023;
        int t = c >> 10, h = (c >> 6) & 15, k = c & 63;
        const float* W = (t == 0) ? Wq : (t == 1) ? Wk : Wv;
        Wbt[o] = f2bf(W[(h * 1024 + d) * 64 + k]);
    }
}

// Wobt[n][c] = Wo[c][n]
__global__ void k_pack_wo(const float* __restrict__ Wo, short* __restrict__ Wobt, int n) {
    int stride = gridDim.x * blockDim.x;
    for (int o = blockIdx.x * blockDim.x + threadIdx.x; o < n; o += stride) {
        int nn = o >> 10, c = o & 1023;
        Wobt[o] = f2bf(Wo[c * 1024 + nn]);
    }
}

// ---------------- GEMM: C[M,N] = A[M,1024] * Bt[N,1024]^T ----------------
// 128x128 tile, BK=64, 256 threads (4 waves in 2x2), 16x16x32 bf16 MFMA.
// LDS tiles XOR-swizzled (byte ^= (row&7)<<4); staged via global_load_lds with
// pre-swizzled per-lane global source (linear LDS dest).
// EPI 0: QKV epilogue (bias, Q*0.125, scatter to [B,H,S,64] bf16)
// EPI 1: fp32 out epilogue (+bo)

template <int EPI>
__launch_bounds__(256)
__global__ void gemm_bf16(const short* __restrict__ Ag, const short* __restrict__ Btg,
                          const float* __restrict__ b0, const float* __restrict__ b1,
                          const float* __restrict__ b2,
                          short* __restrict__ O0, short* __restrict__ O1, short* __restrict__ O2,
                          float* __restrict__ Of) {
    __shared__ short As[128 * 64];
    __shared__ short Bs[128 * 64];
    const int tid = threadIdx.x;
    const int wave = tid >> 6, lane = tid & 63;
    const int wm = wave >> 1, wn = wave & 1;
    const int m0 = blockIdx.y * 128, n0 = blockIdx.x * 128;

    f32x4 acc[4][4] = {};

    const int lr = lane >> 3;          // row within 8-row chunk
    const int cb = (lane & 7) * 16;    // linear byte col
    const int cl = cb ^ (lr << 4);     // pre-swizzled source byte col

    for (int kt = 0; kt < 16; ++kt) {
        __syncthreads();
#pragma unroll
        for (int i = 0; i < 4; ++i) {
            int r8 = wave * 32 + i * 8;
            const char* ga = (const char*)(Ag + (size_t)(m0 + r8 + lr) * 1024 + kt * 64) + cl;
            gload_lds16(ga, &As[r8 * 64]);
            const char* gb = (const char*)(Btg + (size_t)(n0 + r8 + lr) * 1024 + kt * 64) + cl;
            gload_lds16(gb, &Bs[r8 * 64]);
        }
        asm volatile("s_waitcnt vmcnt(0)" ::: "memory");
        __syncthreads();
#pragma unroll
        for (int ks = 0; ks < 2; ++ks) {
            int kb = ks * 64 + (lane >> 4) * 16;
            s16x8 af[4], bf[4];
#pragma unroll
            for (int mf = 0; mf < 4; ++mf) {
                int m = wm * 64 + mf * 16 + (lane & 15);
                af[mf] = *(const s16x8*)&As[m * 64 + ((kb ^ ((m & 7) << 4)) >> 1)];
            }
#pragma unroll
            for (int nf = 0; nf < 4; ++nf) {
                int n = wn * 64 + nf * 16 + (lane & 15);
                bf[nf] = *(const s16x8*)&Bs[n * 64 + ((kb ^ ((n & 7) << 4)) >> 1)];
            }
#pragma unroll
            for (int mf = 0; mf < 4; ++mf)
#pragma unroll
                for (int nf = 0; nf < 4; ++nf)
                    acc[mf][nf] = __builtin_amdgcn_mfma_f32_16x16x32_bf16(af[mf], bf[nf],
                                                                          acc[mf][nf], 0, 0, 0);
        }
    }

    if (EPI == 0) {
#pragma unroll
        for (int nf = 0; nf < 4; ++nf) {
            int n = n0 + wn * 64 + nf * 16 + (lane & 15);
            int t = n >> 10;
            int h = (n >> 6) & 15;
            int kk = n & 63;
            const float* bias = (t == 0) ? b0 : (t == 1) ? b1 : b2;
            short* dst = (t == 0) ? O0 : (t == 1) ? O1 : O2;
            float scale = (t == 0) ? 0.125f : 1.0f;
            float bb = bias[h * 64 + kk];
#pragma unroll
            for (int mf = 0; mf < 4; ++mf) {
#pragma unroll
                for (int r = 0; r < 4; ++r) {
                    int m = m0 + wm * 64 + mf * 16 + (lane >> 4) * 4 + r;
                    int b_ = m >> 11, sp = m & 2047;
                    float v = (acc[mf][nf][r] + bb) * scale;
                    dst[(((size_t)(b_ * 16 + h)) * 2048 + sp) * 64 + kk] = f2bf(v);
                }
            }
        }
    } else {
#pragma unroll
        for (int nf = 0; nf < 4; ++nf) {
            int n = n0 + wn * 64 + nf * 16 + (lane & 15);
            float bb = b0[n];
#pragma unroll
            for (int mf = 0; mf < 4; ++mf) {
#pragma unroll
                for (int r = 0; r < 4; ++r) {
                    int m = m0 + wm * 64 + mf * 16 + (lane >> 4) * 4 + r;
                    Of[(size_t)m * 1024 + n] = acc[mf][nf][r] + bb;
                }
            }
        }
    }
}

// ---------------- causal flash attention ----------------
// grid (32, 64): x = q-tile (reversed for load balance), y = b*16+h
// 64 q-rows per block, 4 waves x 16 rows. KV tiles of 64.

__launch_bounds__(256)
__global__ void attn_fwd(const short* __restrict__ Qb, const short* __restrict__ Kb,
                         const short* __restrict__ Vb, short* __restrict__ Ab) {
    __shared__ short Ks[64 * 64];
    __shared__ short Vt[64 * 64];
    __shared__ short Ps[64 * 64];
    const int tid = threadIdx.x, wave = tid >> 6, lane = tid & 63;
    const int bh = blockIdx.y;
    const int qt = gridDim.x - 1 - blockIdx.x;
    const size_t base = (size_t)bh * 2048 * 64;
    const float NEG_INF = -__builtin_inff();

    // Q fragments in registers (A-operand layout)
    const int qrow = wave * 16 + (lane & 15);
    s16x8 qf[2];
#pragma unroll
    for (int ks = 0; ks < 2; ++ks)
        qf[ks] = *(const s16x8*)&Qb[base + (size_t)(qt * 64 + qrow) * 64 + ks * 32 + (lane >> 4) * 8];

    f32x4 o[4] = {};
    float mrow[4], lrow[4];
#pragma unroll
    for (int r = 0; r < 4; ++r) { mrow[r] = NEG_INF; lrow[r] = 0.f; }

    const int lr = lane >> 3, cb = (lane & 7) * 16, cl = cb ^ (lr << 4);
    const int kkey = tid & 63, vb0 = tid >> 6;

    for (int kt = 0; kt <= qt; ++kt) {
        __syncthreads();
        // stage K tile [64 keys][64 d] via global_load_lds, swizzled
#pragma unroll
        for (int i = 0; i < 2; ++i) {
            int r8 = wave * 16 + i * 8;
            const char* g = (const char*)(Kb + base + (size_t)(kt * 64 + r8 + lr) * 64) + cl;
            gload_lds16(g, &Ks[r8 * 64]);
        }
        // stage V transposed: Vt[v][key], swizzled (reg path)
#pragma unroll
        for (int half = 0; half < 2; ++half) {
            int vb = vb0 + half * 4;
            s16x8 w = *(const s16x8*)&Vb[base + (size_t)(kt * 64 + kkey) * 64 + vb * 8];
#pragma unroll
            for (int j = 0; j < 8; ++j) {
                int v = vb * 8 + j;
                Vt[v * 64 + (((kkey * 2) ^ ((v & 7) << 4)) >> 1)] = w[j];
            }
        }
        asm volatile("s_waitcnt vmcnt(0)" ::: "memory");
        __syncthreads();

        // QK^T: scores[16 q x 64 keys] per wave
        f32x4 sc[4] = {};
#pragma unroll
        for (int ks = 0; ks < 2; ++ks) {
            int kb = ks * 64 + (lane >> 4) * 16;
#pragma unroll
            for (int nf = 0; nf < 4; ++nf) {
                int key = nf * 16 + (lane & 15);
                s16x8 bfr = *(const s16x8*)&Ks[key * 64 + ((kb ^ ((key & 7) << 4)) >> 1)];
                sc[nf] = __builtin_amdgcn_mfma_f32_16x16x32_bf16(qf[ks], bfr, sc[nf], 0, 0, 0);
            }
        }
        // causal mask on diagonal tile
        if (kt == qt) {
#pragma unroll
            for (int nf = 0; nf < 4; ++nf) {
                int key = nf * 16 + (lane & 15);
#pragma unroll
                for (int r = 0; r < 4; ++r) {
                    int q = wave * 16 + (lane >> 4) * 4 + r;
                    if (key > q) sc[nf][r] = NEG_INF;
                }
            }
        }
        // online softmax (per q-row; row lives in a 16-lane group)
#pragma unroll
        for (int r = 0; r < 4; ++r) {
            float tm = fmaxf(fmaxf(sc[0][r], sc[1][r]), fmaxf(sc[2][r], sc[3][r]));
#pragma unroll
            for (int off = 1; off < 16; off <<= 1) tm = fmaxf(tm, __shfl_xor(tm, off));
            float mn = fmaxf(mrow[r], tm);
            float scl = __expf(mrow[r] - mn);
            float rs = 0.f;
#pragma unroll
            for (int nf = 0; nf < 4; ++nf) {
                float p = __expf(sc[nf][r] - mn);
                sc[nf][r] = p;
                rs += p;
            }
#pragma unroll
            for (int off = 1; off < 16; off <<= 1) rs += __shfl_xor(rs, off);
            lrow[r] = lrow[r] * scl + rs;
            mrow[r] = mn;
#pragma unroll
            for (int nf = 0; nf < 4; ++nf) o[nf][r] *= scl;
            // write P (bf16) to swizzled LDS for the PV A-operand
            int q = wave * 16 + (lane >> 4) * 4 + r;
#pragma unroll
            for (int nf = 0; nf < 4; ++nf) {
                int keyb = (nf * 16 + (lane & 15)) * 2;
                Ps[q * 64 + ((keyb ^ ((q & 7) << 4)) >> 1)] = f2bf(sc[nf][r]);
            }
        }
        // PV: o += P[16x64] * V[64x64]
#pragma unroll
        for (int ks = 0; ks < 2; ++ks) {
            int q = wave * 16 + (lane & 15);
            int kb = ks * 64 + (lane >> 4) * 16;
            s16x8 pa = *(const s16x8*)&Ps[q * 64 + ((kb ^ ((q & 7) << 4)) >> 1)];
#pragma unroll
            for (int nf = 0; nf < 4; ++nf) {
                int v = nf * 16 + (lane & 15);
                s16x8 vb_ = *(const s16x8*)&Vt[v * 64 + ((kb ^ ((v & 7) << 4)) >> 1)];
                o[nf] = __builtin_amdgcn_mfma_f32_16x16x32_bf16(pa, vb_, o[nf], 0, 0, 0);
            }
        }
    }

    // epilogue: A[b, s, h*64+v] bf16
    const int b_ = bh >> 4, h = bh & 15;
#pragma unroll
    for (int nf = 0; nf < 4; ++nf) {
#pragma unroll
        for (int r = 0; r < 4; ++r) {
            int q = qt * 64 + wave * 16 + (lane >> 4) * 4 + r;
            float v = o[nf][r] / lrow[r];
            Ab[((size_t)(b_ * 2048 + q)) * 1024 + h * 64 + nf * 16 + (lane & 15)] = f2bf(v);
        }
    }
}

// ---------------- launcher ----------------

extern "C" void kernel_launch(void* const* d_in, const int* in_sizes, int n_in,
                              void* d_out, int out_size, void* d_ws, size_t ws_size,
                              hipStream_t stream) {
    const float* X  = (const float*)d_in[0];
    const float* Wq = (const float*)d_in[1];
    const float* bq = (const float*)d_in[2];
    const float* Wk = (const float*)d_in[3];
    const float* bk = (const float*)d_in[4];
    const float* Wv = (const float*)d_in[5];
    const float* bv = (const float*)d_in[6];
    const float* Wo = (const float*)d_in[7];
    const float* bo = (const float*)d_in[8];
    float* out = (float*)d_out;
    char* ws = (char*)d_ws;

    short* Xb   = (short*)(ws);                 // 16 MB
    short* Wbt  = (short*)(ws + 16777216);      // 6 MB
    short* Wobt = (short*)(ws + 23068672);      // 2 MB
    short* Qb   = (short*)(ws + 25165824);      // 16 MB
    short* Kb   = (short*)(ws + 41943040);      // 16 MB
    short* Vb   = (short*)(ws + 58720256);      // 16 MB
    short* Ab   = (short*)(ws + 75497472);      // 16 MB  (total ~88 MB)

    k_cvt_x<<<2048, 256, 0, stream>>>(X, Xb, 8192 * 1024 / 4);
    k_pack_wqkv<<<2048, 256, 0, stream>>>(Wq, Wk, Wv, Wbt, 3 * 1024 * 1024);
    k_pack_wo<<<1024, 256, 0, stream>>>(Wo, Wobt, 1024 * 1024);

    gemm_bf16<0><<<dim3(24, 64), 256, 0, stream>>>(Xb, Wbt, bq, bk, bv, Qb, Kb, Vb, nullptr);
    attn_fwd<<<dim3(32, 64), 256, 0, stream>>>(Qb, Kb, Vb, Ab);
    gemm_bf16<1><<<dim3(8, 64), 256, 0, stream>>>(Ab, Wobt, bo, nullptr, nullptr,
                                                  nullptr, nullptr, nullptr, out);
}